// Round 3
// baseline (5810.810 us; speedup 1.0000x reference)
//
#include <hip/hip_runtime.h>
#include <hip/hip_fp16.h>
#include <cstdint>
#include <cstddef>

// Sizes (fixed by the problem)
// B=64, T=1024, I=64, H=256, G=3H=768, N=B*T=65536

typedef _Float16 half2_t __attribute__((ext_vector_type(2)));

// Pinned v_dot2_f32_f16: acc += w.h[0]*h.h[0] + w.h[1]*h.h[1]
#define DOT2(acc, w, h) \
    asm("v_dot2_f32_f16 %0, %1, %2, %0" : "+v"(acc) : "v"(w), "v"(h))

__device__ __forceinline__ float fdot2f(unsigned int w, unsigned int h, float acc) {
    __half2 wv = __builtin_bit_cast(__half2, w);
    __half2 hv = __builtin_bit_cast(__half2, h);
    float2 wf = __half22float2(wv), hf = __half22float2(hv);
    return acc + wf.x * hf.x + wf.y * hf.y;
}

// LDS-only barrier: do NOT drain vmcnt (global loads/stores stay in flight).
__device__ __forceinline__ void lds_barrier() {
    asm volatile("s_waitcnt lgkmcnt(0)\n\ts_barrier" ::: "memory");
}

// Pack w_hh [768][256] f32 -> [768][128] of f16-pairs (adjacent k packed)
__global__ void pack_whh(const float* __restrict__ w1, const float* __restrict__ w2,
                         __half2* __restrict__ o1, __half2* __restrict__ o2) {
    int g = blockIdx.x;       // 0..767
    int k2 = threadIdx.x;     // 0..127
    const float* w = blockIdx.y ? w2 : w1;
    __half2* o = blockIdx.y ? o2 : o1;
    float a = w[g * 256 + 2 * k2];
    float b = w[g * 256 + 2 * k2 + 1];
    o[g * 128 + k2] = __floats2half2_rn(a, b);
}

// xw1 = x[65536,64] @ w_ih1[768,64]^T + b_ih1 -> f16 [65536,768]
__global__ __launch_bounds__(256)
void gemm_xw1(const float* __restrict__ A, const float* __restrict__ W,
              const float* __restrict__ bias, __half* __restrict__ out) {
    __shared__ float As[64][65];
    __shared__ float Ws[64][65];
    const int tid = threadIdx.x;
    const int n0 = blockIdx.y * 64, g0 = blockIdx.x * 64;
    for (int idx = tid; idx < 4096; idx += 256) {
        int r = idx >> 6, c = idx & 63;
        As[r][c] = A[(size_t)(n0 + r) * 64 + c];
        Ws[r][c] = W[(size_t)(g0 + r) * 64 + c];
    }
    __syncthreads();
    const int ty = tid >> 4, tx = tid & 15;
    float acc[4][4] = {};
    for (int k = 0; k < 64; ++k) {
        float a[4], w[4];
        #pragma unroll
        for (int i = 0; i < 4; ++i) a[i] = As[ty * 4 + i][k];
        #pragma unroll
        for (int jj = 0; jj < 4; ++jj) w[jj] = Ws[tx * 4 + jj][k];
        #pragma unroll
        for (int i = 0; i < 4; ++i)
            #pragma unroll
            for (int jj = 0; jj < 4; ++jj) acc[i][jj] += a[i] * w[jj];
    }
    #pragma unroll
    for (int jj = 0; jj < 4; ++jj) {
        float bb = bias[g0 + tx * 4 + jj];
        #pragma unroll
        for (int i = 0; i < 4; ++i)
            out[(size_t)(n0 + ty * 4 + i) * 768 + (g0 + tx * 4 + jj)] =
                __float2half(acc[i][jj] + bb);
    }
}

// xw2 = y1[65536,256](f16) @ w_eff[768,256](f16)^T + b_eff -> f16 [65536,768]
__global__ __launch_bounds__(256)
void gemm_xw2(const __half2* __restrict__ A, const __half2* __restrict__ W,
              const float* __restrict__ bias, __half* __restrict__ out) {
    __shared__ __half2 As[64][33];
    __shared__ __half2 Ws[64][33];
    const int tid = threadIdx.x;
    const int n0 = blockIdx.y * 64, g0 = blockIdx.x * 64;
    const int ty = tid >> 4, tx = tid & 15;
    float acc[4][4] = {};
    for (int kc = 0; kc < 4; ++kc) {
        __syncthreads();
        for (int idx = tid; idx < 2048; idx += 256) {
            int r = idx >> 5, c2 = idx & 31;
            As[r][c2] = A[(size_t)(n0 + r) * 128 + kc * 32 + c2];
            Ws[r][c2] = W[(size_t)(g0 + r) * 128 + kc * 32 + c2];
        }
        __syncthreads();
        #pragma unroll 8
        for (int k2 = 0; k2 < 32; ++k2) {
            unsigned int a2[4], w2[4];
            #pragma unroll
            for (int i = 0; i < 4; ++i)
                a2[i] = __builtin_bit_cast(unsigned int, As[ty * 4 + i][k2]);
            #pragma unroll
            for (int jj = 0; jj < 4; ++jj)
                w2[jj] = __builtin_bit_cast(unsigned int, Ws[tx * 4 + jj][k2]);
            #pragma unroll
            for (int i = 0; i < 4; ++i)
                #pragma unroll
                for (int jj = 0; jj < 4; ++jj)
                    acc[i][jj] = fdot2f(w2[jj], a2[i], acc[i][jj]);
        }
    }
    #pragma unroll
    for (int jj = 0; jj < 4; ++jj) {
        float bb = bias[g0 + tx * 4 + jj];
        #pragma unroll
        for (int i = 0; i < 4; ++i)
            out[(size_t)(n0 + ty * 4 + i) * 768 + (g0 + tx * 4 + jj)] =
                __float2half(acc[i][jj] + bb);
    }
}

// GRU recurrence: one block per batch element; thread j owns hidden unit j.
// This round: LDS-only barrier (global loads/stores NOT drained per step),
// xw conversion moved after the dot phase (vmcnt wait lands ~1.5 steps after
// issue), pinned v_dot2_f32_f16, 12 x 32-deep accumulator chains.
template<int LAYER>
__global__ __launch_bounds__(256, 1)
void rec_kernel(const __half2* __restrict__ wpack,  // [768][128] f16-pairs
                const float* __restrict__ b_hh,     // [768]
                const __half* __restrict__ xw,      // [64][1024][768]
                __half* __restrict__ y_out,         // LAYER==1: [64][1024][256]
                float* __restrict__ stats,          // sum[256], sumsq[256]
                float* __restrict__ mx_out,         // LAYER==2: [64][256]
                float* __restrict__ mn_out) {
    __shared__ __align__(16) __half2 hbuf[2][128];
    const int j = threadIdx.x;   // 0..255
    const int b = blockIdx.x;    // 0..63

    uint4 wr[32], wz[32], wn[32];
    const uint4* wp = (const uint4*)wpack;
    #pragma unroll
    for (int q = 0; q < 32; ++q) wr[q] = wp[(size_t)j * 32 + q];
    #pragma unroll
    for (int q = 0; q < 32; ++q) wz[q] = wp[(size_t)(j + 256) * 32 + q];
    #pragma unroll
    for (int q = 0; q < 32; ++q) wn[q] = wp[(size_t)(j + 512) * 32 + q];

    const float br = b_hh[j], bz = b_hh[256 + j], bn = b_hh[512 + j];

    if (j < 128) hbuf[0][j] = __floats2half2_rn(0.f, 0.f);

    float hprev = 0.f, ssum = 0.f, ssq = 0.f;
    float mx = -3.0e38f, mn = 3.0e38f;
    const __half* xwp = xw + (size_t)b * 1024 * 768;
    __half* yp = (LAYER == 1) ? (y_out + (size_t)b * 1024 * 256) : (__half*)nullptr;

    // prefetch t=0
    __half nxr = xwp[j], nxz = xwp[256 + j], nxn = xwp[512 + j];
    __half yhalf = __float2half(0.f);
    __syncthreads();

    for (int t = 0; t < 1024; ++t) {
        // carry forward this step's xw (loaded last step); issue t+1 prefetch now
        __half cxr = nxr, cxz = nxz, cxn = nxn;
        const __half* xq = xwp + (size_t)(t + 1) * 768;
        nxr = xq[j]; nxz = xq[256 + j]; nxn = xq[512 + j];
        // store h_{t-1}: stays in flight across the step-end barrier
        if (LAYER == 1 && t) yp[(size_t)(t - 1) * 256 + j] = yhalf;

        float ar[4] = {br, 0.f, 0.f, 0.f};
        float az[4] = {bz, 0.f, 0.f, 0.f};
        float an[4] = {bn, 0.f, 0.f, 0.f};
        const uint4* h4 = (const uint4*)hbuf[t & 1];
        #pragma unroll
        for (int q = 0; q < 32; ++q) {
            uint4 hq = h4[q];
            DOT2(ar[0], wr[q].x, hq.x);
            DOT2(az[0], wz[q].x, hq.x);
            DOT2(an[0], wn[q].x, hq.x);
            DOT2(ar[1], wr[q].y, hq.y);
            DOT2(az[1], wz[q].y, hq.y);
            DOT2(an[1], wn[q].y, hq.y);
            DOT2(ar[2], wr[q].z, hq.z);
            DOT2(az[2], wz[q].z, hq.z);
            DOT2(an[2], wn[q].z, hq.z);
            DOT2(ar[3], wr[q].w, hq.w);
            DOT2(az[3], wz[q].w, hq.w);
            DOT2(an[3], wn[q].w, hq.w);
        }
        float hr = (ar[0] + ar[1]) + (ar[2] + ar[3]);
        float hz = (az[0] + az[1]) + (az[2] + az[3]);
        float hn = (an[0] + an[1]) + (an[2] + an[3]);
        // xw conversion here: compiler's vmcnt wait for these regs lands
        // ~1.5 steps after the loads were issued.
        float xr = __half2float(cxr);
        float xz = __half2float(cxz);
        float xn = __half2float(cxn);
        float r = 1.f / (1.f + __expf(-(xr + hr)));
        float z = 1.f / (1.f + __expf(-(xz + hz)));
        float pa = xn + r * hn;
        pa = fminf(fmaxf(pa, -15.f), 15.f);
        float e2 = __expf(2.f * pa);
        float nn = (e2 - 1.f) / (e2 + 1.f);
        float h = (1.f - z) * nn + z * hprev;
        hprev = h;
        ssum += h;
        ssq += h * h;
        if (LAYER == 2) { mx = fmaxf(mx, h); mn = fminf(mn, h); }
        yhalf = __float2half(h);
        ((__half*)hbuf[(t + 1) & 1])[j] = yhalf;   // disjoint from read buffer
        lds_barrier();   // LDS-only drain: xw loads / y stores stay in flight
    }
    if (LAYER == 1) yp[(size_t)1023 * 256 + j] = yhalf;
    atomicAdd(&stats[j], ssum);
    atomicAdd(&stats[256 + j], ssq);
    if (LAYER == 2) {
        mx_out[b * 256 + j] = mx;
        mn_out[b * 256 + j] = mn;
    }
}

// Fold BN1 (training-mode batch stats) into layer-2 input weights.
__global__ void fold_bn1(const float* __restrict__ w_ih2, const float* __restrict__ b_ih2,
                         const float* __restrict__ g1, const float* __restrict__ be1,
                         const float* __restrict__ stats1,
                         __half* __restrict__ w_eff, float* __restrict__ b_eff) {
    const int g = blockIdx.x, lane = threadIdx.x;  // 768 blocks x 64 threads
    const float invN = 1.f / 65536.f;
    float partial = 0.f;
    for (int c = lane; c < 256; c += 64) {
        float mu = stats1[c] * invN;
        float var = stats1[256 + c] * invN - mu * mu;
        float s = g1[c] * rsqrtf(var + 1e-5f);
        float sh = be1[c] - mu * s;
        float w = w_ih2[g * 256 + c];
        w_eff[g * 256 + c] = __float2half(w * s);
        partial += w * sh;
    }
    #pragma unroll
    for (int off = 32; off > 0; off >>= 1) partial += __shfl_down(partial, off);
    if (lane == 0) b_eff[g] = b_ih2[g] + partial;
}

// BN2 affine -> time max-pool (max if scale>=0 else min) -> tanh -> FC
__global__ void final_kernel(const float* __restrict__ stats2,
                             const float* __restrict__ mx, const float* __restrict__ mn,
                             const float* __restrict__ g2, const float* __restrict__ be2,
                             const float* __restrict__ w_fc, const float* __restrict__ b_fc,
                             float* __restrict__ out) {
    __shared__ float v[256];
    const int b = blockIdx.x, c = threadIdx.x;
    const float invN = 1.f / 65536.f;
    float mu = stats2[c] * invN;
    float var = stats2[256 + c] * invN - mu * mu;
    float s = g2[c] * rsqrtf(var + 1e-5f);
    float d = be2[c] - mu * s;
    float M = (s >= 0.f) ? mx[b * 256 + c] : mn[b * 256 + c];
    v[c] = tanhf(s * M + d);
    __syncthreads();
    if (c < 128) {
        float acc = b_fc[c];
        for (int k = 0; k < 256; ++k) acc += v[k] * w_fc[c * 256 + k];
        out[b * 128 + c] = acc;
    }
}

extern "C" void kernel_launch(void* const* d_in, const int* in_sizes, int n_in,
                              void* d_out, int out_size, void* d_ws, size_t ws_size,
                              hipStream_t stream) {
    const float* x     = (const float*)d_in[0];
    const float* w_ih1 = (const float*)d_in[1];
    const float* w_hh1 = (const float*)d_in[2];
    const float* b_ih1 = (const float*)d_in[3];
    const float* b_hh1 = (const float*)d_in[4];
    const float* g1    = (const float*)d_in[5];
    const float* be1   = (const float*)d_in[6];
    const float* w_ih2 = (const float*)d_in[7];
    const float* w_hh2 = (const float*)d_in[8];
    const float* b_ih2 = (const float*)d_in[9];
    const float* b_hh2 = (const float*)d_in[10];
    const float* g2    = (const float*)d_in[11];
    const float* be2   = (const float*)d_in[12];
    const float* w_fc  = (const float*)d_in[13];
    const float* b_fc  = (const float*)d_in[14];
    float* out = (float*)d_out;

    char* ws = (char*)d_ws;
    size_t off = 0;
    __half*  xw   = (__half*)(ws + off);  off += (size_t)65536 * 768 * 2;  // shared by both layers
    __half*  y1   = (__half*)(ws + off);  off += (size_t)65536 * 256 * 2;
    __half2* wp1  = (__half2*)(ws + off); off += (size_t)768 * 128 * 4;
    __half2* wp2  = (__half2*)(ws + off); off += (size_t)768 * 128 * 4;
    __half*  weff = (__half*)(ws + off);  off += (size_t)768 * 256 * 2;
    float*   beff = (float*)(ws + off);   off += (size_t)768 * 4;
    float*   stats= (float*)(ws + off);   off += (size_t)1024 * 4;         // sum1,sq1,sum2,sq2
    float*   mx2  = (float*)(ws + off);   off += (size_t)64 * 256 * 4;
    float*   mn2  = (float*)(ws + off);   off += (size_t)64 * 256 * 4;

    hipMemsetAsync(stats, 0, 4096, stream);

    pack_whh<<<dim3(768, 2), dim3(128), 0, stream>>>(w_hh1, w_hh2, wp1, wp2);
    gemm_xw1<<<dim3(12, 1024), dim3(256), 0, stream>>>(x, w_ih1, b_ih1, xw);
    rec_kernel<1><<<dim3(64), dim3(256), 0, stream>>>(wp1, b_hh1, xw, y1, stats,
                                                      (float*)nullptr, (float*)nullptr);
    fold_bn1<<<dim3(768), dim3(64), 0, stream>>>(w_ih2, b_ih2, g1, be1, stats, weff, beff);
    gemm_xw2<<<dim3(12, 1024), dim3(256), 0, stream>>>((const __half2*)y1, (const __half2*)weff,
                                                       beff, xw);
    rec_kernel<2><<<dim3(64), dim3(256), 0, stream>>>(wp2, b_hh2, xw, (__half*)nullptr,
                                                      stats + 512, mx2, mn2);
    final_kernel<<<dim3(64), dim3(256), 0, stream>>>(stats + 512, mx2, mn2, g2, be2,
                                                     w_fc, b_fc, out);
}

// Round 5
// 3149.752 us; speedup vs baseline: 1.8448x; 1.8448x over previous
//
#include <hip/hip_runtime.h>
#include <hip/hip_fp16.h>
#include <cstdint>
#include <cstddef>

// Sizes (fixed by the problem)
// B=64, T=1024, I=64, H=256, G=3H=768, N=B*T=65536

// Pinned v_dot2_f32_f16: acc += w.h[0]*h.h[0] + w.h[1]*h.h[1]
#define DOT2(acc, w, h) \
    asm("v_dot2_f32_f16 %0, %1, %2, %0" : "+v"(acc) : "v"(w), "v"(h))

// LDS-only barrier: do NOT drain vmcnt (global loads/stores stay in flight).
__device__ __forceinline__ void lds_barrier() {
    asm volatile("s_waitcnt lgkmcnt(0)\n\ts_barrier" ::: "memory");
}

// Pack w_hh [768][256] f32 -> [768][128] of f16-pairs (adjacent k packed)
__global__ void pack_whh(const float* __restrict__ w1, const float* __restrict__ w2,
                         __half2* __restrict__ o1, __half2* __restrict__ o2) {
    int g = blockIdx.x;       // 0..767
    int k2 = threadIdx.x;     // 0..127
    const float* w = blockIdx.y ? w2 : w1;
    __half2* o = blockIdx.y ? o2 : o1;
    float a = w[g * 256 + 2 * k2];
    float b = w[g * 256 + 2 * k2 + 1];
    o[g * 128 + k2] = __floats2half2_rn(a, b);
}

// xw1 = x[65536,64] @ w_ih1[768,64]^T + b_ih1 -> f16 [65536,768]
__global__ __launch_bounds__(256)
void gemm_xw1(const float* __restrict__ A, const float* __restrict__ W,
              const float* __restrict__ bias, __half* __restrict__ out) {
    __shared__ float As[64][65];
    __shared__ float Ws[64][65];
    const int tid = threadIdx.x;
    const int n0 = blockIdx.y * 64, g0 = blockIdx.x * 64;
    for (int idx = tid; idx < 4096; idx += 256) {
        int r = idx >> 6, c = idx & 63;
        As[r][c] = A[(size_t)(n0 + r) * 64 + c];
        Ws[r][c] = W[(size_t)(g0 + r) * 64 + c];
    }
    __syncthreads();
    const int ty = tid >> 4, tx = tid & 15;
    float acc[4][4] = {};
    for (int k = 0; k < 64; ++k) {
        float a[4], w[4];
        #pragma unroll
        for (int i = 0; i < 4; ++i) a[i] = As[ty * 4 + i][k];
        #pragma unroll
        for (int jj = 0; jj < 4; ++jj) w[jj] = Ws[tx * 4 + jj][k];
        #pragma unroll
        for (int i = 0; i < 4; ++i)
            #pragma unroll
            for (int jj = 0; jj < 4; ++jj) acc[i][jj] += a[i] * w[jj];
    }
    #pragma unroll
    for (int jj = 0; jj < 4; ++jj) {
        float bb = bias[g0 + tx * 4 + jj];
        #pragma unroll
        for (int i = 0; i < 4; ++i)
            out[(size_t)(n0 + ty * 4 + i) * 768 + (g0 + tx * 4 + jj)] =
                __float2half(acc[i][jj] + bb);
    }
}

// xw2 = y1[65536,256](f16) @ w_eff[768,256](f16)^T + b_eff -> f16 [65536,768]
__global__ __launch_bounds__(256)
void gemm_xw2(const __half2* __restrict__ A, const __half2* __restrict__ W,
              const float* __restrict__ bias, __half* __restrict__ out) {
    __shared__ __half2 As[64][33];
    __shared__ __half2 Ws[64][33];
    const int tid = threadIdx.x;
    const int n0 = blockIdx.y * 64, g0 = blockIdx.x * 64;
    const int ty = tid >> 4, tx = tid & 15;
    float acc[4][4] = {};
    for (int kc = 0; kc < 4; ++kc) {
        __syncthreads();
        for (int idx = tid; idx < 2048; idx += 256) {
            int r = idx >> 5, c2 = idx & 31;
            As[r][c2] = A[(size_t)(n0 + r) * 128 + kc * 32 + c2];
            Ws[r][c2] = W[(size_t)(g0 + r) * 128 + kc * 32 + c2];
        }
        __syncthreads();
        #pragma unroll 8
        for (int k2 = 0; k2 < 32; ++k2) {
            unsigned int a2[4], w2[4];
            #pragma unroll
            for (int i = 0; i < 4; ++i)
                a2[i] = __builtin_bit_cast(unsigned int, As[ty * 4 + i][k2]);
            #pragma unroll
            for (int jj = 0; jj < 4; ++jj)
                w2[jj] = __builtin_bit_cast(unsigned int, Ws[tx * 4 + jj][k2]);
            #pragma unroll
            for (int i = 0; i < 4; ++i)
                #pragma unroll
                for (int jj = 0; jj < 4; ++jj)
                    DOT2(acc[i][jj], w2[jj], a2[i]);
        }
    }
    #pragma unroll
    for (int jj = 0; jj < 4; ++jj) {
        float bb = bias[g0 + tx * 4 + jj];
        #pragma unroll
        for (int i = 0; i < 4; ++i)
            out[(size_t)(n0 + ty * 4 + i) * 768 + (g0 + tx * 4 + jj)] =
                __float2half(acc[i][jj] + bb);
    }
}

// GRU recurrence, K-split by 2: 512 threads/block; thread = (unit j = tid>>1,
// K-half kq = tid&1). Per-thread weights: 48 uint4 = 192 VGPRs -> fits the
// VGPR file (no AGPR copy traffic, the round-2/3 bottleneck). Partner threads
// are adjacent lanes -> 3x __shfl_xor(.,1) combines partial sums. 8 waves =
// 2 waves/SIMD for latency hiding. LDS-only barrier keeps global traffic in
// flight across steps. h halves padded (17 uint4 stride) to decouple banks.
template<int LAYER>
__global__ __launch_bounds__(512, 2)
void rec_kernel(const __half2* __restrict__ wpack,  // [768][128] f16-pairs
                const float* __restrict__ b_hh,     // [768]
                const __half* __restrict__ xw,      // [64][1024][768]
                __half* __restrict__ y_out,         // LAYER==1: [64][1024][256]
                float* __restrict__ stats,          // sum[256], sumsq[256]
                float* __restrict__ mx_out,         // LAYER==2: [64][256]
                float* __restrict__ mn_out) {
    __shared__ __align__(16) uint4 hbuf[2][2][17];  // [buf][K-half][16 uint4 + pad]
    const int tid = threadIdx.x;  // 0..511
    const int j  = tid >> 1;      // hidden unit 0..255
    const int kq = tid & 1;       // K-half
    const int b = blockIdx.x;     // 0..63

    uint4 wr[16], wz[16], wn[16];
    const uint4* wp4 = (const uint4*)wpack;
    const int wbase = kq * 16;
    #pragma unroll
    for (int m = 0; m < 16; ++m) wr[m] = wp4[(size_t)j * 32 + wbase + m];
    #pragma unroll
    for (int m = 0; m < 16; ++m) wz[m] = wp4[(size_t)(j + 256) * 32 + wbase + m];
    #pragma unroll
    for (int m = 0; m < 16; ++m) wn[m] = wp4[(size_t)(j + 512) * 32 + wbase + m];

    const float br = b_hh[j], bz = b_hh[256 + j], bn = b_hh[512 + j];

    if (tid < 34) ((uint4*)hbuf[0])[tid] = uint4{0u, 0u, 0u, 0u};

    float hprev = 0.f, ssum = 0.f, ssq = 0.f;
    float mx = -3.0e38f, mn = 3.0e38f;
    const __half* xwp = xw + (size_t)b * 1024 * 768;
    __half* yp = (LAYER == 1) ? (y_out + (size_t)b * 1024 * 256) : (__half*)nullptr;

    // prefetch t=0
    __half nxr = xwp[j], nxz = xwp[256 + j], nxn = xwp[512 + j];
    __syncthreads();

    for (int t = 0; t < 1024; ++t) {
        __half cxr = nxr, cxz = nxz, cxn = nxn;
        // prefetch t+1 (t=1023 over-read lands in the adjacent ws region; discarded)
        const __half* xq = xwp + (size_t)(t + 1) * 768;
        nxr = xq[j]; nxz = xq[256 + j]; nxn = xq[512 + j];

        float ar0 = 0.f, ar1 = 0.f, az0 = 0.f, az1 = 0.f, an0 = 0.f, an1 = 0.f;
        const uint4* hb = hbuf[t & 1][kq];
        #pragma unroll
        for (int m = 0; m < 16; ++m) {
            uint4 hq = hb[m];
            DOT2(ar0, wr[m].x, hq.x);
            DOT2(az0, wz[m].x, hq.x);
            DOT2(an0, wn[m].x, hq.x);
            DOT2(ar1, wr[m].y, hq.y);
            DOT2(az1, wz[m].y, hq.y);
            DOT2(an1, wn[m].y, hq.y);
            DOT2(ar0, wr[m].z, hq.z);
            DOT2(az0, wz[m].z, hq.z);
            DOT2(an0, wn[m].z, hq.z);
            DOT2(ar1, wr[m].w, hq.w);
            DOT2(az1, wz[m].w, hq.w);
            DOT2(an1, wn[m].w, hq.w);
        }
        float hr = ar0 + ar1, hz = az0 + az1, hn = an0 + an1;
        // combine K-halves (partner is adjacent lane, same wave)
        hr += __shfl_xor(hr, 1);
        hz += __shfl_xor(hz, 1);
        hn += __shfl_xor(hn, 1);
        hr += br; hz += bz; hn += bn;

        float xr = __half2float(cxr);
        float xz = __half2float(cxz);
        float xn = __half2float(cxn);
        float r = 1.f / (1.f + __expf(-(xr + hr)));
        float z = 1.f / (1.f + __expf(-(xz + hz)));
        float pa = xn + r * hn;
        pa = fminf(fmaxf(pa, -15.f), 15.f);
        float e2 = __expf(2.f * pa);
        float nn = (e2 - 1.f) / (e2 + 1.f);
        float h = (1.f - z) * nn + z * hprev;
        hprev = h;
        ssum += h;
        ssq += h * h;
        if (LAYER == 2) { mx = fmaxf(mx, h); mn = fminf(mn, h); }
        __half yh = __float2half(h);
        if (kq == 0) {
            ((__half*)hbuf[(t + 1) & 1][j >> 7])[j & 127] = yh;  // disjoint buffer
            if (LAYER == 1) yp[(size_t)t * 256 + j] = yh;        // stays in flight
        }
        lds_barrier();   // LDS-only drain: xw loads / y stores not drained
    }
    if (kq == 0) {
        atomicAdd(&stats[j], ssum);
        atomicAdd(&stats[256 + j], ssq);
        if (LAYER == 2) {
            mx_out[b * 256 + j] = mx;
            mn_out[b * 256 + j] = mn;
        }
    }
}

// Fold BN1 (training-mode batch stats) into layer-2 input weights.
__global__ void fold_bn1(const float* __restrict__ w_ih2, const float* __restrict__ b_ih2,
                         const float* __restrict__ g1, const float* __restrict__ be1,
                         const float* __restrict__ stats1,
                         __half* __restrict__ w_eff, float* __restrict__ b_eff) {
    const int g = blockIdx.x, lane = threadIdx.x;  // 768 blocks x 64 threads
    const float invN = 1.f / 65536.f;
    float partial = 0.f;
    for (int c = lane; c < 256; c += 64) {
        float mu = stats1[c] * invN;
        float var = stats1[256 + c] * invN - mu * mu;
        float s = g1[c] * rsqrtf(var + 1e-5f);
        float sh = be1[c] - mu * s;
        float w = w_ih2[g * 256 + c];
        w_eff[g * 256 + c] = __float2half(w * s);
        partial += w * sh;
    }
    #pragma unroll
    for (int off = 32; off > 0; off >>= 1) partial += __shfl_down(partial, off);
    if (lane == 0) b_eff[g] = b_ih2[g] + partial;
}

// BN2 affine -> time max-pool (max if scale>=0 else min) -> tanh -> FC
__global__ void final_kernel(const float* __restrict__ stats2,
                             const float* __restrict__ mx, const float* __restrict__ mn,
                             const float* __restrict__ g2, const float* __restrict__ be2,
                             const float* __restrict__ w_fc, const float* __restrict__ b_fc,
                             float* __restrict__ out) {
    __shared__ float v[256];
    const int b = blockIdx.x, c = threadIdx.x;
    const float invN = 1.f / 65536.f;
    float mu = stats2[c] * invN;
    float var = stats2[256 + c] * invN - mu * mu;
    float s = g2[c] * rsqrtf(var + 1e-5f);
    float d = be2[c] - mu * s;
    float M = (s >= 0.f) ? mx[b * 256 + c] : mn[b * 256 + c];
    v[c] = tanhf(s * M + d);
    __syncthreads();
    if (c < 128) {
        float acc = b_fc[c];
        for (int k = 0; k < 256; ++k) acc += v[k] * w_fc[c * 256 + k];
        out[b * 128 + c] = acc;
    }
}

extern "C" void kernel_launch(void* const* d_in, const int* in_sizes, int n_in,
                              void* d_out, int out_size, void* d_ws, size_t ws_size,
                              hipStream_t stream) {
    const float* x     = (const float*)d_in[0];
    const float* w_ih1 = (const float*)d_in[1];
    const float* w_hh1 = (const float*)d_in[2];
    const float* b_ih1 = (const float*)d_in[3];
    const float* b_hh1 = (const float*)d_in[4];
    const float* g1    = (const float*)d_in[5];
    const float* be1   = (const float*)d_in[6];
    const float* w_ih2 = (const float*)d_in[7];
    const float* w_hh2 = (const float*)d_in[8];
    const float* b_ih2 = (const float*)d_in[9];
    const float* b_hh2 = (const float*)d_in[10];
    const float* g2    = (const float*)d_in[11];
    const float* be2   = (const float*)d_in[12];
    const float* w_fc  = (const float*)d_in[13];
    const float* b_fc  = (const float*)d_in[14];
    float* out = (float*)d_out;

    char* ws = (char*)d_ws;
    size_t off = 0;
    __half*  xw   = (__half*)(ws + off);  off += (size_t)65536 * 768 * 2;  // shared by both layers
    __half*  y1   = (__half*)(ws + off);  off += (size_t)65536 * 256 * 2;
    __half2* wp1  = (__half2*)(ws + off); off += (size_t)768 * 128 * 4;
    __half2* wp2  = (__half2*)(ws + off); off += (size_t)768 * 128 * 4;
    __half*  weff = (__half*)(ws + off);  off += (size_t)768 * 256 * 2;
    float*   beff = (float*)(ws + off);   off += (size_t)768 * 4;
    float*   stats= (float*)(ws + off);   off += (size_t)1024 * 4;         // sum1,sq1,sum2,sq2
    float*   mx2  = (float*)(ws + off);   off += (size_t)64 * 256 * 4;
    float*   mn2  = (float*)(ws + off);   off += (size_t)64 * 256 * 4;

    hipMemsetAsync(stats, 0, 4096, stream);

    pack_whh<<<dim3(768, 2), dim3(128), 0, stream>>>(w_hh1, w_hh2, wp1, wp2);
    gemm_xw1<<<dim3(12, 1024), dim3(256), 0, stream>>>(x, w_ih1, b_ih1, xw);
    rec_kernel<1><<<dim3(64), dim3(512), 0, stream>>>(wp1, b_hh1, xw, y1, stats,
                                                      (float*)nullptr, (float*)nullptr);
    fold_bn1<<<dim3(768), dim3(64), 0, stream>>>(w_ih2, b_ih2, g1, be1, stats, weff, beff);
    gemm_xw2<<<dim3(12, 1024), dim3(256), 0, stream>>>((const __half2*)y1, (const __half2*)weff,
                                                       beff, xw);
    rec_kernel<2><<<dim3(64), dim3(512), 0, stream>>>(wp2, b_hh2, xw, (__half*)nullptr,
                                                      stats + 512, mx2, mn2);
    final_kernel<<<dim3(64), dim3(256), 0, stream>>>(stats + 512, mx2, mn2, g2, be2,
                                                     w_fc, b_fc, out);
}

// Round 8
// 3042.737 us; speedup vs baseline: 1.9097x; 1.0352x over previous
//
#include <hip/hip_runtime.h>
#include <hip/hip_fp16.h>
#include <cstdint>
#include <cstddef>

// Sizes (fixed by the problem)
// B=64, T=1024, I=64, H=256, G=3H=768, N=B*T=65536

typedef _Float16 half2_t __attribute__((ext_vector_type(2)));

// Builtin dot2: compiler may source operands from AGPRs directly (unified
// file) -- no forced v_accvgpr_read copies like a "v"-constrained asm.
__device__ __forceinline__ float fdot2f(unsigned int w, unsigned int h, float acc) {
    return __builtin_amdgcn_fdot2(__builtin_bit_cast(half2_t, w),
                                  __builtin_bit_cast(half2_t, h), acc, false);
}

// Pinned v_dot2_f32_f16 for the GEMM (operands there are freshly-read VGPRs).
#define DOT2(acc, w, h) \
    asm("v_dot2_f32_f16 %0, %1, %2, %0" : "+v"(acc) : "v"(w), "v"(h))

// LDS-only barrier: do NOT drain vmcnt (global loads/stores stay in flight).
__device__ __forceinline__ void lds_barrier() {
    asm volatile("s_waitcnt lgkmcnt(0)\n\ts_barrier" ::: "memory");
}

// Pack w_hh [768][256] f32 -> [768][128] of f16-pairs (adjacent k packed)
__global__ void pack_whh(const float* __restrict__ w1, const float* __restrict__ w2,
                         __half2* __restrict__ o1, __half2* __restrict__ o2) {
    int g = blockIdx.x;       // 0..767
    int k2 = threadIdx.x;     // 0..127
    const float* w = blockIdx.y ? w2 : w1;
    __half2* o = blockIdx.y ? o2 : o1;
    float a = w[g * 256 + 2 * k2];
    float b = w[g * 256 + 2 * k2 + 1];
    o[g * 128 + k2] = __floats2half2_rn(a, b);
}

// xw1 = x[65536,64] @ w_ih1[768,64]^T + b_ih1 -> f16 [65536,768]
__global__ __launch_bounds__(256)
void gemm_xw1(const float* __restrict__ A, const float* __restrict__ W,
              const float* __restrict__ bias, __half* __restrict__ out) {
    __shared__ float As[64][65];
    __shared__ float Ws[64][65];
    const int tid = threadIdx.x;
    const int n0 = blockIdx.y * 64, g0 = blockIdx.x * 64;
    for (int idx = tid; idx < 4096; idx += 256) {
        int r = idx >> 6, c = idx & 63;
        As[r][c] = A[(size_t)(n0 + r) * 64 + c];
        Ws[r][c] = W[(size_t)(g0 + r) * 64 + c];
    }
    __syncthreads();
    const int ty = tid >> 4, tx = tid & 15;
    float acc[4][4] = {};
    for (int k = 0; k < 64; ++k) {
        float a[4], w[4];
        #pragma unroll
        for (int i = 0; i < 4; ++i) a[i] = As[ty * 4 + i][k];
        #pragma unroll
        for (int jj = 0; jj < 4; ++jj) w[jj] = Ws[tx * 4 + jj][k];
        #pragma unroll
        for (int i = 0; i < 4; ++i)
            #pragma unroll
            for (int jj = 0; jj < 4; ++jj) acc[i][jj] += a[i] * w[jj];
    }
    #pragma unroll
    for (int jj = 0; jj < 4; ++jj) {
        float bb = bias[g0 + tx * 4 + jj];
        #pragma unroll
        for (int i = 0; i < 4; ++i)
            out[(size_t)(n0 + ty * 4 + i) * 768 + (g0 + tx * 4 + jj)] =
                __float2half(acc[i][jj] + bb);
    }
}

// xw2 = y1[65536,256](f16) @ w_eff[768,256](f16)^T + b_eff -> f16 [65536,768]
__global__ __launch_bounds__(256)
void gemm_xw2(const __half2* __restrict__ A, const __half2* __restrict__ W,
              const float* __restrict__ bias, __half* __restrict__ out) {
    __shared__ __half2 As[64][33];
    __shared__ __half2 Ws[64][33];
    const int tid = threadIdx.x;
    const int n0 = blockIdx.y * 64, g0 = blockIdx.x * 64;
    const int ty = tid >> 4, tx = tid & 15;
    float acc[4][4] = {};
    for (int kc = 0; kc < 4; ++kc) {
        __syncthreads();
        for (int idx = tid; idx < 2048; idx += 256) {
            int r = idx >> 5, c2 = idx & 31;
            As[r][c2] = A[(size_t)(n0 + r) * 128 + kc * 32 + c2];
            Ws[r][c2] = W[(size_t)(g0 + r) * 128 + kc * 32 + c2];
        }
        __syncthreads();
        #pragma unroll 8
        for (int k2 = 0; k2 < 32; ++k2) {
            unsigned int a2[4], w2[4];
            #pragma unroll
            for (int i = 0; i < 4; ++i)
                a2[i] = __builtin_bit_cast(unsigned int, As[ty * 4 + i][k2]);
            #pragma unroll
            for (int jj = 0; jj < 4; ++jj)
                w2[jj] = __builtin_bit_cast(unsigned int, Ws[tx * 4 + jj][k2]);
            #pragma unroll
            for (int i = 0; i < 4; ++i)
                #pragma unroll
                for (int jj = 0; jj < 4; ++jj)
                    DOT2(acc[i][jj], w2[jj], a2[i]);
        }
    }
    #pragma unroll
    for (int jj = 0; jj < 4; ++jj) {
        float bb = bias[g0 + tx * 4 + jj];
        #pragma unroll
        for (int i = 0; i < 4; ++i)
            out[(size_t)(n0 + ty * 4 + i) * 768 + (g0 + tx * 4 + jj)] =
                __float2half(acc[i][jj] + bb);
    }
}

// GRU recurrence, 2-units x K-quarter partition: 512 threads/block.
// thread = (pair p = tid>>2, K-quarter kq = tid&3); owns units {2p, 2p+1}.
// Weights: 6 rows x 8 uint4 = 192 regs/thread (same as before), but each h
// word read from LDS now feeds 6 dots instead of 3 -> LDS h-traffic HALVED
// (8 ds_read_b128/thread/step). Partial sums combined with a 2-level
// shfl_xor(1,2) butterfly inside each 4-lane quad; lanes kq=0/1 own the
// tail for units 2p/2p+1. K-quarter LDS slices padded to 144B stride
// (banks 0/4/8/12 -> conflict-free). Builtin fdot2 (no AGPR-copy traffic).
template<int LAYER>
__global__ __launch_bounds__(512, 2)
void rec_kernel(const __half2* __restrict__ wpack,  // [768][128] f16-pairs
                const float* __restrict__ b_hh,     // [768]
                const __half* __restrict__ xw,      // [64][1024][768]
                __half* __restrict__ y_out,         // LAYER==1: [64][1024][256]
                float* __restrict__ stats,          // sum[256], sumsq[256]
                float* __restrict__ mx_out,         // LAYER==2: [64][256]
                float* __restrict__ mn_out) {
    __shared__ __align__(16) uint4 hb4[2][4][9];   // [buf][K-quarter][8 uint4 + pad]
    const int tid = threadIdx.x;   // 0..511
    const int p   = tid >> 2;      // unit pair 0..127
    const int kq  = tid & 3;       // K-quarter
    const int kql = kq & 1;
    const int u   = 2 * p + kql;   // tail unit this lane finishes
    const int b   = blockIdx.x;    // 0..63

    // Weight fragments: rows {2p,2p+1} x gates {r,z,n}, K-quarter kq.
    uint4 Wr0[8], Wr1[8], Wz0[8], Wz1[8], Wn0[8], Wn1[8];
    {
        const uint4* wp4 = (const uint4*)wpack;
        const int mb = kq * 8;
        #pragma unroll
        for (int m = 0; m < 8; ++m) Wr0[m] = wp4[(size_t)(2 * p) * 32 + mb + m];
        #pragma unroll
        for (int m = 0; m < 8; ++m) Wr1[m] = wp4[(size_t)(2 * p + 1) * 32 + mb + m];
        #pragma unroll
        for (int m = 0; m < 8; ++m) Wz0[m] = wp4[(size_t)(2 * p + 256) * 32 + mb + m];
        #pragma unroll
        for (int m = 0; m < 8; ++m) Wz1[m] = wp4[(size_t)(2 * p + 257) * 32 + mb + m];
        #pragma unroll
        for (int m = 0; m < 8; ++m) Wn0[m] = wp4[(size_t)(2 * p + 512) * 32 + mb + m];
        #pragma unroll
        for (int m = 0; m < 8; ++m) Wn1[m] = wp4[(size_t)(2 * p + 513) * 32 + mb + m];
    }

    const float bru = b_hh[u], bzu = b_hh[256 + u], bnu = b_hh[512 + u];

    if (tid < 36) ((uint4*)hb4)[tid] = uint4{0u, 0u, 0u, 0u};  // zero buffer 0

    float hprev = 0.f, ssum = 0.f, ssq = 0.f;
    float mx = -3.0e38f, mn = 3.0e38f;
    const __half* xwp = xw + (size_t)b * 1024 * 768;
    __half* yp = (LAYER == 1) ? (y_out + (size_t)b * 1024 * 256) : (__half*)nullptr;

    // prefetch t=0 (lanes kq=2,3 mirror kq=0,1 -- same cacheline)
    __half nxr = xwp[u], nxz = xwp[256 + u], nxn = xwp[512 + u];
    __syncthreads();

    for (int t = 0; t < 1024; ++t) {
        __half cxr = nxr, cxz = nxz, cxn = nxn;
        // prefetch t+1 (t=1023 over-read lands in the adjacent ws region; discarded)
        const __half* xq = xwp + (size_t)(t + 1) * 768;
        nxr = xq[u]; nxz = xq[256 + u]; nxn = xq[512 + u];

        float r0 = 0.f, r1 = 0.f, z0 = 0.f, z1 = 0.f, n0 = 0.f, n1 = 0.f;
        const uint4* hq = hb4[t & 1][kq];
        #pragma unroll
        for (int m = 0; m < 8; ++m) {
            uint4 h = hq[m];
            r0 = fdot2f(Wr0[m].x, h.x, r0);
            r1 = fdot2f(Wr1[m].x, h.x, r1);
            z0 = fdot2f(Wz0[m].x, h.x, z0);
            z1 = fdot2f(Wz1[m].x, h.x, z1);
            n0 = fdot2f(Wn0[m].x, h.x, n0);
            n1 = fdot2f(Wn1[m].x, h.x, n1);
            r0 = fdot2f(Wr0[m].y, h.y, r0);
            r1 = fdot2f(Wr1[m].y, h.y, r1);
            z0 = fdot2f(Wz0[m].y, h.y, z0);
            z1 = fdot2f(Wz1[m].y, h.y, z1);
            n0 = fdot2f(Wn0[m].y, h.y, n0);
            n1 = fdot2f(Wn1[m].y, h.y, n1);
            r0 = fdot2f(Wr0[m].z, h.z, r0);
            r1 = fdot2f(Wr1[m].z, h.z, r1);
            z0 = fdot2f(Wz0[m].z, h.z, z0);
            z1 = fdot2f(Wz1[m].z, h.z, z1);
            n0 = fdot2f(Wn0[m].z, h.z, n0);
            n1 = fdot2f(Wn1[m].z, h.z, n1);
            r0 = fdot2f(Wr0[m].w, h.w, r0);
            r1 = fdot2f(Wr1[m].w, h.w, r1);
            z0 = fdot2f(Wz0[m].w, h.w, z0);
            z1 = fdot2f(Wz1[m].w, h.w, z1);
            n0 = fdot2f(Wn0[m].w, h.w, n0);
            n1 = fdot2f(Wn1[m].w, h.w, n1);
        }
        // combine K-quarters within the 4-lane quad
        r0 += __shfl_xor(r0, 1); r0 += __shfl_xor(r0, 2);
        r1 += __shfl_xor(r1, 1); r1 += __shfl_xor(r1, 2);
        z0 += __shfl_xor(z0, 1); z0 += __shfl_xor(z0, 2);
        z1 += __shfl_xor(z1, 1); z1 += __shfl_xor(z1, 2);
        n0 += __shfl_xor(n0, 1); n0 += __shfl_xor(n0, 2);
        n1 += __shfl_xor(n1, 1); n1 += __shfl_xor(n1, 2);

        float hr = (kql ? r1 : r0) + bru;
        float hz = (kql ? z1 : z0) + bzu;
        float hn = (kql ? n1 : n0) + bnu;

        float xr = __half2float(cxr);
        float xz = __half2float(cxz);
        float xn = __half2float(cxn);
        float r = 1.f / (1.f + __expf(-(xr + hr)));
        float z = 1.f / (1.f + __expf(-(xz + hz)));
        float pa = xn + r * hn;
        pa = fminf(fmaxf(pa, -15.f), 15.f);
        float e2 = __expf(2.f * pa);
        float nn = (e2 - 1.f) / (e2 + 1.f);
        float h = (1.f - z) * nn + z * hprev;
        hprev = h;
        ssum += h;
        ssq += h * h;
        if (LAYER == 2) { mx = fmaxf(mx, h); mn = fminf(mn, h); }
        __half yh = __float2half(h);
        if (kq < 2) {
            // write h_t for unit u into the other buffer (padded layout)
            ((__half*)hb4[(t + 1) & 1][u >> 6])[u & 63] = yh;
            if (LAYER == 1) yp[(size_t)t * 256 + u] = yh;   // stays in flight
        }
        lds_barrier();   // LDS-only drain: xw loads / y stores not drained
    }
    if (kq < 2) {
        atomicAdd(&stats[u], ssum);
        atomicAdd(&stats[256 + u], ssq);
        if (LAYER == 2) {
            mx_out[b * 256 + u] = mx;
            mn_out[b * 256 + u] = mn;
        }
    }
}

// Fold BN1 (training-mode batch stats) into layer-2 input weights.
__global__ void fold_bn1(const float* __restrict__ w_ih2, const float* __restrict__ b_ih2,
                         const float* __restrict__ g1, const float* __restrict__ be1,
                         const float* __restrict__ stats1,
                         __half* __restrict__ w_eff, float* __restrict__ b_eff) {
    const int g = blockIdx.x, lane = threadIdx.x;  // 768 blocks x 64 threads
    const float invN = 1.f / 65536.f;
    float partial = 0.f;
    for (int c = lane; c < 256; c += 64) {
        float mu = stats1[c] * invN;
        float var = stats1[256 + c] * invN - mu * mu;
        float s = g1[c] * rsqrtf(var + 1e-5f);
        float sh = be1[c] - mu * s;
        float w = w_ih2[g * 256 + c];
        w_eff[g * 256 + c] = __float2half(w * s);
        partial += w * sh;
    }
    #pragma unroll
    for (int off = 32; off > 0; off >>= 1) partial += __shfl_down(partial, off);
    if (lane == 0) b_eff[g] = b_ih2[g] + partial;
}

// BN2 affine -> time max-pool (max if scale>=0 else min) -> tanh -> FC
__global__ void final_kernel(const float* __restrict__ stats2,
                             const float* __restrict__ mx, const float* __restrict__ mn,
                             const float* __restrict__ g2, const float* __restrict__ be2,
                             const float* __restrict__ w_fc, const float* __restrict__ b_fc,
                             float* __restrict__ out) {
    __shared__ float v[256];
    const int b = blockIdx.x, c = threadIdx.x;
    const float invN = 1.f / 65536.f;
    float mu = stats2[c] * invN;
    float var = stats2[256 + c] * invN - mu * mu;
    float s = g2[c] * rsqrtf(var + 1e-5f);
    float d = be2[c] - mu * s;
    float M = (s >= 0.f) ? mx[b * 256 + c] : mn[b * 256 + c];
    v[c] = tanhf(s * M + d);
    __syncthreads();
    if (c < 128) {
        float acc = b_fc[c];
        for (int k = 0; k < 256; ++k) acc += v[k] * w_fc[c * 256 + k];
        out[b * 128 + c] = acc;
    }
}

extern "C" void kernel_launch(void* const* d_in, const int* in_sizes, int n_in,
                              void* d_out, int out_size, void* d_ws, size_t ws_size,
                              hipStream_t stream) {
    const float* x     = (const float*)d_in[0];
    const float* w_ih1 = (const float*)d_in[1];
    const float* w_hh1 = (const float*)d_in[2];
    const float* b_ih1 = (const float*)d_in[3];
    const float* b_hh1 = (const float*)d_in[4];
    const float* g1    = (const float*)d_in[5];
    const float* be1   = (const float*)d_in[6];
    const float* w_ih2 = (const float*)d_in[7];
    const float* w_hh2 = (const float*)d_in[8];
    const float* b_ih2 = (const float*)d_in[9];
    const float* b_hh2 = (const float*)d_in[10];
    const float* g2    = (const float*)d_in[11];
    const float* be2   = (const float*)d_in[12];
    const float* w_fc  = (const float*)d_in[13];
    const float* b_fc  = (const float*)d_in[14];
    float* out = (float*)d_out;

    char* ws = (char*)d_ws;
    size_t off = 0;
    __half*  xw   = (__half*)(ws + off);  off += (size_t)65536 * 768 * 2;  // shared by both layers
    __half*  y1   = (__half*)(ws + off);  off += (size_t)65536 * 256 * 2;
    __half2* wp1  = (__half2*)(ws + off); off += (size_t)768 * 128 * 4;
    __half2* wp2  = (__half2*)(ws + off); off += (size_t)768 * 128 * 4;
    __half*  weff = (__half*)(ws + off);  off += (size_t)768 * 256 * 2;
    float*   beff = (float*)(ws + off);   off += (size_t)768 * 4;
    float*   stats= (float*)(ws + off);   off += (size_t)1024 * 4;         // sum1,sq1,sum2,sq2
    float*   mx2  = (float*)(ws + off);   off += (size_t)64 * 256 * 4;
    float*   mn2  = (float*)(ws + off);   off += (size_t)64 * 256 * 4;

    hipMemsetAsync(stats, 0, 4096, stream);

    pack_whh<<<dim3(768, 2), dim3(128), 0, stream>>>(w_hh1, w_hh2, wp1, wp2);
    gemm_xw1<<<dim3(12, 1024), dim3(256), 0, stream>>>(x, w_ih1, b_ih1, xw);
    rec_kernel<1><<<dim3(64), dim3(512), 0, stream>>>(wp1, b_hh1, xw, y1, stats,
                                                      (float*)nullptr, (float*)nullptr);
    fold_bn1<<<dim3(768), dim3(64), 0, stream>>>(w_ih2, b_ih2, g1, be1, stats, weff, beff);
    gemm_xw2<<<dim3(12, 1024), dim3(256), 0, stream>>>((const __half2*)y1, (const __half2*)weff,
                                                       beff, xw);
    rec_kernel<2><<<dim3(64), dim3(512), 0, stream>>>(wp2, b_hh2, xw, (__half*)nullptr,
                                                      stats + 512, mx2, mn2);
    final_kernel<<<dim3(64), dim3(256), 0, stream>>>(stats + 512, mx2, mn2, g2, be2,
                                                     w_fc, b_fc, out);
}

// Round 11
// 2996.907 us; speedup vs baseline: 1.9389x; 1.0153x over previous
//
#include <hip/hip_runtime.h>
#include <hip/hip_fp16.h>
#include <cstdint>
#include <cstddef>

// Sizes (fixed by the problem)
// B=64, T=1024, I=64, H=256, G=3H=768, N=B*T=65536

// Pinned v_dot2_f32_f16: acc += w.h[0]*h.h[0] + w.h[1]*h.h[1]
// "v" constraints force weight operands into ARCH VGPRs: with 192 weight
// regs/thread (fits the 256-arch cap at 2 waves/SIMD), AGPR-homing would
// cost a copy per use -> allocator should keep weights in arch VGPRs.
#define DOT2(acc, w, h) \
    asm("v_dot2_f32_f16 %0, %1, %2, %0" : "+v"(acc) : "v"(w), "v"(h))

// DPP quad-perm butterfly add (replaces ds_swizzle shuffles: no LDS pipe,
// no lgkmcnt serialization). 0xB1 = xor1 within quad, 0x4E = xor2.
// CTL must be a compile-time constant (builtin requirement).
template<int CTL>
__device__ __forceinline__ float dpp_add(float x) {
    int t = __builtin_amdgcn_update_dpp(0, __builtin_bit_cast(int, x),
                                        CTL, 0xF, 0xF, true);
    return x + __builtin_bit_cast(float, t);
}

// LDS-only barrier: do NOT drain vmcnt (global loads/stores stay in flight).
__device__ __forceinline__ void lds_barrier() {
    asm volatile("s_waitcnt lgkmcnt(0)\n\ts_barrier" ::: "memory");
}

// Pack w_hh [768][256] f32 -> [768][128] of f16-pairs (adjacent k packed)
__global__ void pack_whh(const float* __restrict__ w1, const float* __restrict__ w2,
                         __half2* __restrict__ o1, __half2* __restrict__ o2) {
    int g = blockIdx.x;       // 0..767
    int k2 = threadIdx.x;     // 0..127
    const float* w = blockIdx.y ? w2 : w1;
    __half2* o = blockIdx.y ? o2 : o1;
    float a = w[g * 256 + 2 * k2];
    float b = w[g * 256 + 2 * k2 + 1];
    o[g * 128 + k2] = __floats2half2_rn(a, b);
}

// xw1 = x[65536,64] @ w_ih1[768,64]^T + b_ih1 -> f16 [65536,768]
__global__ __launch_bounds__(256)
void gemm_xw1(const float* __restrict__ A, const float* __restrict__ W,
              const float* __restrict__ bias, __half* __restrict__ out) {
    __shared__ float As[64][65];
    __shared__ float Ws[64][65];
    const int tid = threadIdx.x;
    const int n0 = blockIdx.y * 64, g0 = blockIdx.x * 64;
    for (int idx = tid; idx < 4096; idx += 256) {
        int r = idx >> 6, c = idx & 63;
        As[r][c] = A[(size_t)(n0 + r) * 64 + c];
        Ws[r][c] = W[(size_t)(g0 + r) * 64 + c];
    }
    __syncthreads();
    const int ty = tid >> 4, tx = tid & 15;
    float acc[4][4] = {};
    for (int k = 0; k < 64; ++k) {
        float a[4], w[4];
        #pragma unroll
        for (int i = 0; i < 4; ++i) a[i] = As[ty * 4 + i][k];
        #pragma unroll
        for (int jj = 0; jj < 4; ++jj) w[jj] = Ws[tx * 4 + jj][k];
        #pragma unroll
        for (int i = 0; i < 4; ++i)
            #pragma unroll
            for (int jj = 0; jj < 4; ++jj) acc[i][jj] += a[i] * w[jj];
    }
    #pragma unroll
    for (int jj = 0; jj < 4; ++jj) {
        float bb = bias[g0 + tx * 4 + jj];
        #pragma unroll
        for (int i = 0; i < 4; ++i)
            out[(size_t)(n0 + ty * 4 + i) * 768 + (g0 + tx * 4 + jj)] =
                __float2half(acc[i][jj] + bb);
    }
}

// xw2 = y1[65536,256](f16) @ w_eff[768,256](f16)^T + b_eff -> f16 [65536,768]
__global__ __launch_bounds__(256)
void gemm_xw2(const __half2* __restrict__ A, const __half2* __restrict__ W,
              const float* __restrict__ bias, __half* __restrict__ out) {
    __shared__ __half2 As[64][33];
    __shared__ __half2 Ws[64][33];
    const int tid = threadIdx.x;
    const int n0 = blockIdx.y * 64, g0 = blockIdx.x * 64;
    const int ty = tid >> 4, tx = tid & 15;
    float acc[4][4] = {};
    for (int kc = 0; kc < 4; ++kc) {
        __syncthreads();
        for (int idx = tid; idx < 2048; idx += 256) {
            int r = idx >> 5, c2 = idx & 31;
            As[r][c2] = A[(size_t)(n0 + r) * 128 + kc * 32 + c2];
            Ws[r][c2] = W[(size_t)(g0 + r) * 128 + kc * 32 + c2];
        }
        __syncthreads();
        #pragma unroll 8
        for (int k2 = 0; k2 < 32; ++k2) {
            unsigned int a2[4], w2[4];
            #pragma unroll
            for (int i = 0; i < 4; ++i)
                a2[i] = __builtin_bit_cast(unsigned int, As[ty * 4 + i][k2]);
            #pragma unroll
            for (int jj = 0; jj < 4; ++jj)
                w2[jj] = __builtin_bit_cast(unsigned int, Ws[tx * 4 + jj][k2]);
            #pragma unroll
            for (int i = 0; i < 4; ++i)
                #pragma unroll
                for (int jj = 0; jj < 4; ++jj)
                    DOT2(acc[i][jj], w2[jj], a2[i]);
        }
    }
    #pragma unroll
    for (int jj = 0; jj < 4; ++jj) {
        float bb = bias[g0 + tx * 4 + jj];
        #pragma unroll
        for (int i = 0; i < 4; ++i)
            out[(size_t)(n0 + ty * 4 + i) * 768 + (g0 + tx * 4 + jj)] =
                __float2half(acc[i][jj] + bb);
    }
}

// GRU recurrence, 2-units x K-quarter partition: 512 threads/block.
// thread = (pair p = tid>>2, K-quarter kq = tid&3); owns units {2p, 2p+1}.
// Weights: 6 rows x 8 uint4 = 192 regs/thread, asm-"v"-pinned at every dot
// so the allocator homes them in ARCH VGPRs (no AGPR copy per use).
// Quad reduction via DPP butterfly (no ds_swizzle / lgkmcnt on the path).
// LDS-only barrier keeps global traffic in flight across steps.
template<int LAYER>
__global__ __launch_bounds__(512, 2)
void rec_kernel(const __half2* __restrict__ wpack,  // [768][128] f16-pairs
                const float* __restrict__ b_hh,     // [768]
                const __half* __restrict__ xw,      // [64][1024][768]
                __half* __restrict__ y_out,         // LAYER==1: [64][1024][256]
                float* __restrict__ stats,          // sum[256], sumsq[256]
                float* __restrict__ mx_out,         // LAYER==2: [64][256]
                float* __restrict__ mn_out) {
    __shared__ __align__(16) uint4 hb4[2][4][9];   // [buf][K-quarter][8 uint4 + pad]
    const int tid = threadIdx.x;   // 0..511
    const int p   = tid >> 2;      // unit pair 0..127
    const int kq  = tid & 3;       // K-quarter
    const int kql = kq & 1;
    const int u   = 2 * p + kql;   // tail unit this lane finishes
    const int b   = blockIdx.x;    // 0..63

    // Weight fragments: rows {2p,2p+1} x gates {r,z,n}, K-quarter kq.
    uint4 Wr0[8], Wr1[8], Wz0[8], Wz1[8], Wn0[8], Wn1[8];
    {
        const uint4* wp4 = (const uint4*)wpack;
        const int mb = kq * 8;
        #pragma unroll
        for (int m = 0; m < 8; ++m) Wr0[m] = wp4[(size_t)(2 * p) * 32 + mb + m];
        #pragma unroll
        for (int m = 0; m < 8; ++m) Wr1[m] = wp4[(size_t)(2 * p + 1) * 32 + mb + m];
        #pragma unroll
        for (int m = 0; m < 8; ++m) Wz0[m] = wp4[(size_t)(2 * p + 256) * 32 + mb + m];
        #pragma unroll
        for (int m = 0; m < 8; ++m) Wz1[m] = wp4[(size_t)(2 * p + 257) * 32 + mb + m];
        #pragma unroll
        for (int m = 0; m < 8; ++m) Wn0[m] = wp4[(size_t)(2 * p + 512) * 32 + mb + m];
        #pragma unroll
        for (int m = 0; m < 8; ++m) Wn1[m] = wp4[(size_t)(2 * p + 513) * 32 + mb + m];
    }

    const float bru = b_hh[u], bzu = b_hh[256 + u], bnu = b_hh[512 + u];

    if (tid < 36) ((uint4*)hb4)[tid] = uint4{0u, 0u, 0u, 0u};  // zero buffer 0

    float hprev = 0.f, ssum = 0.f, ssq = 0.f;
    float mx = -3.0e38f, mn = 3.0e38f;
    const __half* xwp = xw + (size_t)b * 1024 * 768;
    __half* yp = (LAYER == 1) ? (y_out + (size_t)b * 1024 * 256) : (__half*)nullptr;

    // prefetch t=0 (lanes kq=2,3 mirror kq=0,1 -- same cacheline)
    __half nxr = xwp[u], nxz = xwp[256 + u], nxn = xwp[512 + u];
    __syncthreads();

    for (int t = 0; t < 1024; ++t) {
        __half cxr = nxr, cxz = nxz, cxn = nxn;
        // prefetch t+1 (t=1023 over-read lands in the adjacent ws region; discarded)
        const __half* xq = xwp + (size_t)(t + 1) * 768;
        nxr = xq[u]; nxz = xq[256 + u]; nxn = xq[512 + u];

        float r0 = 0.f, r1 = 0.f, z0 = 0.f, z1 = 0.f, n0 = 0.f, n1 = 0.f;
        const uint4* hq = hb4[t & 1][kq];
        #pragma unroll
        for (int m = 0; m < 8; ++m) {
            uint4 h = hq[m];
            DOT2(r0, Wr0[m].x, h.x);
            DOT2(r1, Wr1[m].x, h.x);
            DOT2(z0, Wz0[m].x, h.x);
            DOT2(z1, Wz1[m].x, h.x);
            DOT2(n0, Wn0[m].x, h.x);
            DOT2(n1, Wn1[m].x, h.x);
            DOT2(r0, Wr0[m].y, h.y);
            DOT2(r1, Wr1[m].y, h.y);
            DOT2(z0, Wz0[m].y, h.y);
            DOT2(z1, Wz1[m].y, h.y);
            DOT2(n0, Wn0[m].y, h.y);
            DOT2(n1, Wn1[m].y, h.y);
            DOT2(r0, Wr0[m].z, h.z);
            DOT2(r1, Wr1[m].z, h.z);
            DOT2(z0, Wz0[m].z, h.z);
            DOT2(z1, Wz1[m].z, h.z);
            DOT2(n0, Wn0[m].z, h.z);
            DOT2(n1, Wn1[m].z, h.z);
            DOT2(r0, Wr0[m].w, h.w);
            DOT2(r1, Wr1[m].w, h.w);
            DOT2(z0, Wz0[m].w, h.w);
            DOT2(z1, Wz1[m].w, h.w);
            DOT2(n0, Wn0[m].w, h.w);
            DOT2(n1, Wn1[m].w, h.w);
        }
        // combine K-quarters within the 4-lane quad (DPP butterfly, VALU-only)
        r0 = dpp_add<0xB1>(r0); r0 = dpp_add<0x4E>(r0);
        r1 = dpp_add<0xB1>(r1); r1 = dpp_add<0x4E>(r1);
        z0 = dpp_add<0xB1>(z0); z0 = dpp_add<0x4E>(z0);
        z1 = dpp_add<0xB1>(z1); z1 = dpp_add<0x4E>(z1);
        n0 = dpp_add<0xB1>(n0); n0 = dpp_add<0x4E>(n0);
        n1 = dpp_add<0xB1>(n1); n1 = dpp_add<0x4E>(n1);

        float hr = (kql ? r1 : r0) + bru;
        float hz = (kql ? z1 : z0) + bzu;
        float hn = (kql ? n1 : n0) + bnu;

        float xr = __half2float(cxr);
        float xz = __half2float(cxz);
        float xn = __half2float(cxn);
        float r = 1.f / (1.f + __expf(-(xr + hr)));
        float z = 1.f / (1.f + __expf(-(xz + hz)));
        float pa = xn + r * hn;
        pa = fminf(fmaxf(pa, -15.f), 15.f);
        float e2 = __expf(2.f * pa);
        float nn = (e2 - 1.f) / (e2 + 1.f);
        float h = (1.f - z) * nn + z * hprev;
        hprev = h;
        ssum += h;
        ssq += h * h;
        if (LAYER == 2) { mx = fmaxf(mx, h); mn = fminf(mn, h); }
        __half yh = __float2half(h);
        if (kq < 2) {
            // write h_t for unit u into the other buffer (padded layout)
            ((__half*)hb4[(t + 1) & 1][u >> 6])[u & 63] = yh;
            if (LAYER == 1) yp[(size_t)t * 256 + u] = yh;   // stays in flight
        }
        lds_barrier();   // LDS-only drain: xw loads / y stores not drained
    }
    if (kq < 2) {
        atomicAdd(&stats[u], ssum);
        atomicAdd(&stats[256 + u], ssq);
        if (LAYER == 2) {
            mx_out[b * 256 + u] = mx;
            mn_out[b * 256 + u] = mn;
        }
    }
}

// Fold BN1 (training-mode batch stats) into layer-2 input weights.
__global__ void fold_bn1(const float* __restrict__ w_ih2, const float* __restrict__ b_ih2,
                         const float* __restrict__ g1, const float* __restrict__ be1,
                         const float* __restrict__ stats1,
                         __half* __restrict__ w_eff, float* __restrict__ b_eff) {
    const int g = blockIdx.x, lane = threadIdx.x;  // 768 blocks x 64 threads
    const float invN = 1.f / 65536.f;
    float partial = 0.f;
    for (int c = lane; c < 256; c += 64) {
        float mu = stats1[c] * invN;
        float var = stats1[256 + c] * invN - mu * mu;
        float s = g1[c] * rsqrtf(var + 1e-5f);
        float sh = be1[c] - mu * s;
        float w = w_ih2[g * 256 + c];
        w_eff[g * 256 + c] = __float2half(w * s);
        partial += w * sh;
    }
    #pragma unroll
    for (int off = 32; off > 0; off >>= 1) partial += __shfl_down(partial, off);
    if (lane == 0) b_eff[g] = b_ih2[g] + partial;
}

// BN2 affine -> time max-pool (max if scale>=0 else min) -> tanh -> FC
__global__ void final_kernel(const float* __restrict__ stats2,
                             const float* __restrict__ mx, const float* __restrict__ mn,
                             const float* __restrict__ g2, const float* __restrict__ be2,
                             const float* __restrict__ w_fc, const float* __restrict__ b_fc,
                             float* __restrict__ out) {
    __shared__ float v[256];
    const int b = blockIdx.x, c = threadIdx.x;
    const float invN = 1.f / 65536.f;
    float mu = stats2[c] * invN;
    float var = stats2[256 + c] * invN - mu * mu;
    float s = g2[c] * rsqrtf(var + 1e-5f);
    float d = be2[c] - mu * s;
    float M = (s >= 0.f) ? mx[b * 256 + c] : mn[b * 256 + c];
    v[c] = tanhf(s * M + d);
    __syncthreads();
    if (c < 128) {
        float acc = b_fc[c];
        for (int k = 0; k < 256; ++k) acc += v[k] * w_fc[c * 256 + k];
        out[b * 128 + c] = acc;
    }
}

extern "C" void kernel_launch(void* const* d_in, const int* in_sizes, int n_in,
                              void* d_out, int out_size, void* d_ws, size_t ws_size,
                              hipStream_t stream) {
    const float* x     = (const float*)d_in[0];
    const float* w_ih1 = (const float*)d_in[1];
    const float* w_hh1 = (const float*)d_in[2];
    const float* b_ih1 = (const float*)d_in[3];
    const float* b_hh1 = (const float*)d_in[4];
    const float* g1    = (const float*)d_in[5];
    const float* be1   = (const float*)d_in[6];
    const float* w_ih2 = (const float*)d_in[7];
    const float* w_hh2 = (const float*)d_in[8];
    const float* b_ih2 = (const float*)d_in[9];
    const float* b_hh2 = (const float*)d_in[10];
    const float* g2    = (const float*)d_in[11];
    const float* be2   = (const float*)d_in[12];
    const float* w_fc  = (const float*)d_in[13];
    const float* b_fc  = (const float*)d_in[14];
    float* out = (float*)d_out;

    char* ws = (char*)d_ws;
    size_t off = 0;
    __half*  xw   = (__half*)(ws + off);  off += (size_t)65536 * 768 * 2;  // shared by both layers
    __half*  y1   = (__half*)(ws + off);  off += (size_t)65536 * 256 * 2;
    __half2* wp1  = (__half2*)(ws + off); off += (size_t)768 * 128 * 4;
    __half2* wp2  = (__half2*)(ws + off); off += (size_t)768 * 128 * 4;
    __half*  weff = (__half*)(ws + off);  off += (size_t)768 * 256 * 2;
    float*   beff = (float*)(ws + off);   off += (size_t)768 * 4;
    float*   stats= (float*)(ws + off);   off += (size_t)1024 * 4;         // sum1,sq1,sum2,sq2
    float*   mx2  = (float*)(ws + off);   off += (size_t)64 * 256 * 4;
    float*   mn2  = (float*)(ws + off);   off += (size_t)64 * 256 * 4;

    (void)hipMemsetAsync(stats, 0, 4096, stream);

    pack_whh<<<dim3(768, 2), dim3(128), 0, stream>>>(w_hh1, w_hh2, wp1, wp2);
    gemm_xw1<<<dim3(12, 1024), dim3(256), 0, stream>>>(x, w_ih1, b_ih1, xw);
    rec_kernel<1><<<dim3(64), dim3(512), 0, stream>>>(wp1, b_hh1, xw, y1, stats,
                                                      (float*)nullptr, (float*)nullptr);
    fold_bn1<<<dim3(768), dim3(64), 0, stream>>>(w_ih2, b_ih2, g1, be1, stats, weff, beff);
    gemm_xw2<<<dim3(12, 1024), dim3(256), 0, stream>>>((const __half2*)y1, (const __half2*)weff,
                                                       beff, xw);
    rec_kernel<2><<<dim3(64), dim3(512), 0, stream>>>(wp2, b_hh2, xw, (__half*)nullptr,
                                                      stats + 512, mx2, mn2);
    final_kernel<<<dim3(64), dim3(256), 0, stream>>>(stats + 512, mx2, mn2, g2, be2,
                                                     w_fc, b_fc, out);
}

// Round 13
// 2995.767 us; speedup vs baseline: 1.9397x; 1.0004x over previous
//
#include <hip/hip_runtime.h>
#include <hip/hip_fp16.h>
#include <cstdint>
#include <cstddef>

// Sizes (fixed by the problem)
// B=64, T=1024, I=64, H=256, G=3H=768, N=B*T=65536

// Pinned v_dot2_f32_f16: acc += w.h[0]*h.h[0] + w.h[1]*h.h[1]
#define DOT2(acc, w, h) \
    asm("v_dot2_f32_f16 %0, %1, %2, %0" : "+v"(acc) : "v"(w), "v"(h))

// Live-range pin on a single 32-bit value ("+v" on uint4 is unsupported --
// "tied indirect register inputs" -- so pin per component). Makes the loaded
// word an opaque asm result: the compiler CANNOT sink/rematerialize the
// global load into the t-loop. (VGPR_Count=120 over rounds 5-11 proves it
// was re-streaming all 393KB of w_hh from L2 every step = the bottleneck.)
#define PIN(x) asm volatile("" : "+v"(x))
#define PIN4(q) do { PIN(q.x); PIN(q.y); PIN(q.z); PIN(q.w); } while (0)

// DPP quad-perm butterfly add. 0xB1 = xor1 within quad, 0x4E = xor2.
template<int CTL>
__device__ __forceinline__ float dpp_add(float x) {
    int t = __builtin_amdgcn_update_dpp(0, __builtin_bit_cast(int, x),
                                        CTL, 0xF, 0xF, true);
    return x + __builtin_bit_cast(float, t);
}

// LDS-only barrier: do NOT drain vmcnt (global loads/stores stay in flight).
__device__ __forceinline__ void lds_barrier() {
    asm volatile("s_waitcnt lgkmcnt(0)\n\ts_barrier" ::: "memory");
}

// Pack w_hh [768][256] f32 -> [768][128] of f16-pairs (adjacent k packed)
__global__ void pack_whh(const float* __restrict__ w1, const float* __restrict__ w2,
                         __half2* __restrict__ o1, __half2* __restrict__ o2) {
    int g = blockIdx.x;       // 0..767
    int k2 = threadIdx.x;     // 0..127
    const float* w = blockIdx.y ? w2 : w1;
    __half2* o = blockIdx.y ? o2 : o1;
    float a = w[g * 256 + 2 * k2];
    float b = w[g * 256 + 2 * k2 + 1];
    o[g * 128 + k2] = __floats2half2_rn(a, b);
}

// xw1 = x[65536,64] @ w_ih1[768,64]^T + b_ih1 -> f16 [65536,768]
__global__ __launch_bounds__(256)
void gemm_xw1(const float* __restrict__ A, const float* __restrict__ W,
              const float* __restrict__ bias, __half* __restrict__ out) {
    __shared__ float As[64][65];
    __shared__ float Ws[64][65];
    const int tid = threadIdx.x;
    const int n0 = blockIdx.y * 64, g0 = blockIdx.x * 64;
    for (int idx = tid; idx < 4096; idx += 256) {
        int r = idx >> 6, c = idx & 63;
        As[r][c] = A[(size_t)(n0 + r) * 64 + c];
        Ws[r][c] = W[(size_t)(g0 + r) * 64 + c];
    }
    __syncthreads();
    const int ty = tid >> 4, tx = tid & 15;
    float acc[4][4] = {};
    for (int k = 0; k < 64; ++k) {
        float a[4], w[4];
        #pragma unroll
        for (int i = 0; i < 4; ++i) a[i] = As[ty * 4 + i][k];
        #pragma unroll
        for (int jj = 0; jj < 4; ++jj) w[jj] = Ws[tx * 4 + jj][k];
        #pragma unroll
        for (int i = 0; i < 4; ++i)
            #pragma unroll
            for (int jj = 0; jj < 4; ++jj) acc[i][jj] += a[i] * w[jj];
    }
    #pragma unroll
    for (int jj = 0; jj < 4; ++jj) {
        float bb = bias[g0 + tx * 4 + jj];
        #pragma unroll
        for (int i = 0; i < 4; ++i)
            out[(size_t)(n0 + ty * 4 + i) * 768 + (g0 + tx * 4 + jj)] =
                __float2half(acc[i][jj] + bb);
    }
}

// xw2 = y1[65536,256](f16) @ w_eff[768,256](f16)^T + b_eff -> f16 [65536,768]
__global__ __launch_bounds__(256)
void gemm_xw2(const __half2* __restrict__ A, const __half2* __restrict__ W,
              const float* __restrict__ bias, __half* __restrict__ out) {
    __shared__ __half2 As[64][33];
    __shared__ __half2 Ws[64][33];
    const int tid = threadIdx.x;
    const int n0 = blockIdx.y * 64, g0 = blockIdx.x * 64;
    const int ty = tid >> 4, tx = tid & 15;
    float acc[4][4] = {};
    for (int kc = 0; kc < 4; ++kc) {
        __syncthreads();
        for (int idx = tid; idx < 2048; idx += 256) {
            int r = idx >> 5, c2 = idx & 31;
            As[r][c2] = A[(size_t)(n0 + r) * 128 + kc * 32 + c2];
            Ws[r][c2] = W[(size_t)(g0 + r) * 128 + kc * 32 + c2];
        }
        __syncthreads();
        #pragma unroll 8
        for (int k2 = 0; k2 < 32; ++k2) {
            unsigned int a2[4], w2[4];
            #pragma unroll
            for (int i = 0; i < 4; ++i)
                a2[i] = __builtin_bit_cast(unsigned int, As[ty * 4 + i][k2]);
            #pragma unroll
            for (int jj = 0; jj < 4; ++jj)
                w2[jj] = __builtin_bit_cast(unsigned int, Ws[tx * 4 + jj][k2]);
            #pragma unroll
            for (int i = 0; i < 4; ++i)
                #pragma unroll
                for (int jj = 0; jj < 4; ++jj)
                    DOT2(acc[i][jj], w2[jj], a2[i]);
        }
    }
    #pragma unroll
    for (int jj = 0; jj < 4; ++jj) {
        float bb = bias[g0 + tx * 4 + jj];
        #pragma unroll
        for (int i = 0; i < 4; ++i)
            out[(size_t)(n0 + ty * 4 + i) * 768 + (g0 + tx * 4 + jj)] =
                __float2half(acc[i][jj] + bb);
    }
}

// GRU recurrence, 2-units x K-quarter partition: 512 threads/block.
// thread = (pair p = tid>>2, K-quarter kq = tid&3); owns units {2p, 2p+1}.
// Weights: 192 regs/thread, loaded ONCE and pinned live via empty asm
// (prevents the load-sinking that re-streamed 393KB/step from L2).
// 192 + ~45 working fits the 256/wave budget at 2 waves/SIMD.
template<int LAYER>
__global__ __launch_bounds__(512, 2)
void rec_kernel(const __half2* __restrict__ wpack,  // [768][128] f16-pairs
                const float* __restrict__ b_hh,     // [768]
                const __half* __restrict__ xw,      // [64][1024][768]
                __half* __restrict__ y_out,         // LAYER==1: [64][1024][256]
                float* __restrict__ stats,          // sum[256], sumsq[256]
                float* __restrict__ mx_out,         // LAYER==2: [64][256]
                float* __restrict__ mn_out) {
    __shared__ __align__(16) uint4 hb4[2][4][9];   // [buf][K-quarter][8 uint4 + pad]
    const int tid = threadIdx.x;   // 0..511
    const int p   = tid >> 2;      // unit pair 0..127
    const int kq  = tid & 3;       // K-quarter
    const int kql = kq & 1;
    const int u   = 2 * p + kql;   // tail unit this lane finishes
    const int b   = blockIdx.x;    // 0..63

    // Weight fragments: rows {2p,2p+1} x gates {r,z,n}, K-quarter kq.
    uint4 Wr0[8], Wr1[8], Wz0[8], Wz1[8], Wn0[8], Wn1[8];
    {
        const uint4* wp4 = (const uint4*)wpack;
        const int mb = kq * 8;
        #pragma unroll
        for (int m = 0; m < 8; ++m) Wr0[m] = wp4[(size_t)(2 * p) * 32 + mb + m];
        #pragma unroll
        for (int m = 0; m < 8; ++m) Wr1[m] = wp4[(size_t)(2 * p + 1) * 32 + mb + m];
        #pragma unroll
        for (int m = 0; m < 8; ++m) Wz0[m] = wp4[(size_t)(2 * p + 256) * 32 + mb + m];
        #pragma unroll
        for (int m = 0; m < 8; ++m) Wz1[m] = wp4[(size_t)(2 * p + 257) * 32 + mb + m];
        #pragma unroll
        for (int m = 0; m < 8; ++m) Wn0[m] = wp4[(size_t)(2 * p + 512) * 32 + mb + m];
        #pragma unroll
        for (int m = 0; m < 8; ++m) Wn1[m] = wp4[(size_t)(2 * p + 513) * 32 + mb + m];
        // Pin every 32-bit weight word: opaque asm results can't be re-loaded.
        #pragma unroll
        for (int m = 0; m < 8; ++m) {
            PIN4(Wr0[m]); PIN4(Wr1[m]);
            PIN4(Wz0[m]); PIN4(Wz1[m]);
            PIN4(Wn0[m]); PIN4(Wn1[m]);
        }
    }

    const float bru = b_hh[u], bzu = b_hh[256 + u], bnu = b_hh[512 + u];

    if (tid < 36) ((uint4*)hb4)[tid] = uint4{0u, 0u, 0u, 0u};  // zero buffer 0

    float hprev = 0.f, ssum = 0.f, ssq = 0.f;
    float mx = -3.0e38f, mn = 3.0e38f;
    const __half* xwp = xw + (size_t)b * 1024 * 768;
    __half* yp = (LAYER == 1) ? (y_out + (size_t)b * 1024 * 256) : (__half*)nullptr;

    // prefetch t=0 (lanes kq=2,3 mirror kq=0,1 -- same cacheline)
    __half nxr = xwp[u], nxz = xwp[256 + u], nxn = xwp[512 + u];
    __syncthreads();

    for (int t = 0; t < 1024; ++t) {
        __half cxr = nxr, cxz = nxz, cxn = nxn;
        // prefetch t+1 (t=1023 over-read lands in the adjacent ws region; discarded)
        const __half* xq = xwp + (size_t)(t + 1) * 768;
        nxr = xq[u]; nxz = xq[256 + u]; nxn = xq[512 + u];

        float r0 = 0.f, r1 = 0.f, z0 = 0.f, z1 = 0.f, n0 = 0.f, n1 = 0.f;
        const uint4* hq = hb4[t & 1][kq];
        #pragma unroll
        for (int m = 0; m < 8; ++m) {
            uint4 h = hq[m];
            DOT2(r0, Wr0[m].x, h.x);
            DOT2(r1, Wr1[m].x, h.x);
            DOT2(z0, Wz0[m].x, h.x);
            DOT2(z1, Wz1[m].x, h.x);
            DOT2(n0, Wn0[m].x, h.x);
            DOT2(n1, Wn1[m].x, h.x);
            DOT2(r0, Wr0[m].y, h.y);
            DOT2(r1, Wr1[m].y, h.y);
            DOT2(z0, Wz0[m].y, h.y);
            DOT2(z1, Wz1[m].y, h.y);
            DOT2(n0, Wn0[m].y, h.y);
            DOT2(n1, Wn1[m].y, h.y);
            DOT2(r0, Wr0[m].z, h.z);
            DOT2(r1, Wr1[m].z, h.z);
            DOT2(z0, Wz0[m].z, h.z);
            DOT2(z1, Wz1[m].z, h.z);
            DOT2(n0, Wn0[m].z, h.z);
            DOT2(n1, Wn1[m].z, h.z);
            DOT2(r0, Wr0[m].w, h.w);
            DOT2(r1, Wr1[m].w, h.w);
            DOT2(z0, Wz0[m].w, h.w);
            DOT2(z1, Wz1[m].w, h.w);
            DOT2(n0, Wn0[m].w, h.w);
            DOT2(n1, Wn1[m].w, h.w);
        }
        // combine K-quarters within the 4-lane quad (DPP butterfly, VALU-only)
        r0 = dpp_add<0xB1>(r0); r0 = dpp_add<0x4E>(r0);
        r1 = dpp_add<0xB1>(r1); r1 = dpp_add<0x4E>(r1);
        z0 = dpp_add<0xB1>(z0); z0 = dpp_add<0x4E>(z0);
        z1 = dpp_add<0xB1>(z1); z1 = dpp_add<0x4E>(z1);
        n0 = dpp_add<0xB1>(n0); n0 = dpp_add<0x4E>(n0);
        n1 = dpp_add<0xB1>(n1); n1 = dpp_add<0x4E>(n1);

        float hr = (kql ? r1 : r0) + bru;
        float hz = (kql ? z1 : z0) + bzu;
        float hn = (kql ? n1 : n0) + bnu;

        float xr = __half2float(cxr);
        float xz = __half2float(cxz);
        float xn = __half2float(cxn);
        float r = 1.f / (1.f + __expf(-(xr + hr)));
        float z = 1.f / (1.f + __expf(-(xz + hz)));
        float pa = xn + r * hn;
        pa = fminf(fmaxf(pa, -15.f), 15.f);
        float e2 = __expf(2.f * pa);
        float nn = (e2 - 1.f) / (e2 + 1.f);
        float h = (1.f - z) * nn + z * hprev;
        hprev = h;
        ssum += h;
        ssq += h * h;
        if (LAYER == 2) { mx = fmaxf(mx, h); mn = fminf(mn, h); }
        __half yh = __float2half(h);
        if (kq < 2) {
            // write h_t for unit u into the other buffer (padded layout)
            ((__half*)hb4[(t + 1) & 1][u >> 6])[u & 63] = yh;
            if (LAYER == 1) yp[(size_t)t * 256 + u] = yh;   // stays in flight
        }
        lds_barrier();   // LDS-only drain: xw loads / y stores not drained
    }
    if (kq < 2) {
        atomicAdd(&stats[u], ssum);
        atomicAdd(&stats[256 + u], ssq);
        if (LAYER == 2) {
            mx_out[b * 256 + u] = mx;
            mn_out[b * 256 + u] = mn;
        }
    }
}

// Fold BN1 (training-mode batch stats) into layer-2 input weights.
__global__ void fold_bn1(const float* __restrict__ w_ih2, const float* __restrict__ b_ih2,
                         const float* __restrict__ g1, const float* __restrict__ be1,
                         const float* __restrict__ stats1,
                         __half* __restrict__ w_eff, float* __restrict__ b_eff) {
    const int g = blockIdx.x, lane = threadIdx.x;  // 768 blocks x 64 threads
    const float invN = 1.f / 65536.f;
    float partial = 0.f;
    for (int c = lane; c < 256; c += 64) {
        float mu = stats1[c] * invN;
        float var = stats1[256 + c] * invN - mu * mu;
        float s = g1[c] * rsqrtf(var + 1e-5f);
        float sh = be1[c] - mu * s;
        float w = w_ih2[g * 256 + c];
        w_eff[g * 256 + c] = __float2half(w * s);
        partial += w * sh;
    }
    #pragma unroll
    for (int off = 32; off > 0; off >>= 1) partial += __shfl_down(partial, off);
    if (lane == 0) b_eff[g] = b_ih2[g] + partial;
}

// BN2 affine -> time max-pool (max if scale>=0 else min) -> tanh -> FC
__global__ void final_kernel(const float* __restrict__ stats2,
                             const float* __restrict__ mx, const float* __restrict__ mn,
                             const float* __restrict__ g2, const float* __restrict__ be2,
                             const float* __restrict__ w_fc, const float* __restrict__ b_fc,
                             float* __restrict__ out) {
    __shared__ float v[256];
    const int b = blockIdx.x, c = threadIdx.x;
    const float invN = 1.f / 65536.f;
    float mu = stats2[c] * invN;
    float var = stats2[256 + c] * invN - mu * mu;
    float s = g2[c] * rsqrtf(var + 1e-5f);
    float d = be2[c] - mu * s;
    float M = (s >= 0.f) ? mx[b * 256 + c] : mn[b * 256 + c];
    v[c] = tanhf(s * M + d);
    __syncthreads();
    if (c < 128) {
        float acc = b_fc[c];
        for (int k = 0; k < 256; ++k) acc += v[k] * w_fc[c * 256 + k];
        out[b * 128 + c] = acc;
    }
}

extern "C" void kernel_launch(void* const* d_in, const int* in_sizes, int n_in,
                              void* d_out, int out_size, void* d_ws, size_t ws_size,
                              hipStream_t stream) {
    const float* x     = (const float*)d_in[0];
    const float* w_ih1 = (const float*)d_in[1];
    const float* w_hh1 = (const float*)d_in[2];
    const float* b_ih1 = (const float*)d_in[3];
    const float* b_hh1 = (const float*)d_in[4];
    const float* g1    = (const float*)d_in[5];
    const float* be1   = (const float*)d_in[6];
    const float* w_ih2 = (const float*)d_in[7];
    const float* w_hh2 = (const float*)d_in[8];
    const float* b_ih2 = (const float*)d_in[9];
    const float* b_hh2 = (const float*)d_in[10];
    const float* g2    = (const float*)d_in[11];
    const float* be2   = (const float*)d_in[12];
    const float* w_fc  = (const float*)d_in[13];
    const float* b_fc  = (const float*)d_in[14];
    float* out = (float*)d_out;

    char* ws = (char*)d_ws;
    size_t off = 0;
    __half*  xw   = (__half*)(ws + off);  off += (size_t)65536 * 768 * 2;  // shared by both layers
    __half*  y1   = (__half*)(ws + off);  off += (size_t)65536 * 256 * 2;
    __half2* wp1  = (__half2*)(ws + off); off += (size_t)768 * 128 * 4;
    __half2* wp2  = (__half2*)(ws + off); off += (size_t)768 * 128 * 4;
    __half*  weff = (__half*)(ws + off);  off += (size_t)768 * 256 * 2;
    float*   beff = (float*)(ws + off);   off += (size_t)768 * 4;
    float*   stats= (float*)(ws + off);   off += (size_t)1024 * 4;         // sum1,sq1,sum2,sq2
    float*   mx2  = (float*)(ws + off);   off += (size_t)64 * 256 * 4;
    float*   mn2  = (float*)(ws + off);   off += (size_t)64 * 256 * 4;

    (void)hipMemsetAsync(stats, 0, 4096, stream);

    pack_whh<<<dim3(768, 2), dim3(128), 0, stream>>>(w_hh1, w_hh2, wp1, wp2);
    gemm_xw1<<<dim3(12, 1024), dim3(256), 0, stream>>>(x, w_ih1, b_ih1, xw);
    rec_kernel<1><<<dim3(64), dim3(512), 0, stream>>>(wp1, b_hh1, xw, y1, stats,
                                                      (float*)nullptr, (float*)nullptr);
    fold_bn1<<<dim3(768), dim3(64), 0, stream>>>(w_ih2, b_ih2, g1, be1, stats, weff, beff);
    gemm_xw2<<<dim3(12, 1024), dim3(256), 0, stream>>>((const __half2*)y1, (const __half2*)weff,
                                                       beff, xw);
    rec_kernel<2><<<dim3(64), dim3(512), 0, stream>>>(wp2, b_hh2, xw, (__half*)nullptr,
                                                      stats + 512, mx2, mn2);
    final_kernel<<<dim3(64), dim3(256), 0, stream>>>(stats + 512, mx2, mn2, g2, be2,
                                                     w_fc, b_fc, out);
}